// Round 15
// baseline (282.919 us; speedup 1.0000x reference)
//
#include <hip/hip_runtime.h>
#include <math.h>

#define NNODES 10000
#define NEDGES 100000
#define NE 10

typedef float v2f __attribute__((ext_vector_type(2)));
typedef unsigned short u16x4 __attribute__((ext_vector_type(4)));

// ---------------- compile-time Clebsch-Gordan (port of reference) ----------------
struct Cplx { double re, im; };

constexpr double cfact(int n){ double r=1.0; for(int i=2;i<=n;++i) r*=i; return r; }

constexpr double csqrt_(double x){
  if (x<=0.0) return 0.0;
  double g = x<1.0 ? 1.0 : x;
  for (int it=0; it<64; ++it){ double ng = 0.5*(g + x/g); if (ng==g) break; g = ng; }
  return g;
}

constexpr double cg_coeff(int j1,int m1,int j2,int m2,int j3,int m3){
  if (m1+m2!=m3) return 0.0;
  int lo = j1>j2 ? j1-j2 : j2-j1;
  if (j3<lo || j3>j1+j2) return 0.0;
  if (m1<-j1||m1>j1||m2<-j2||m2>j2||m3<-j3||m3>j3) return 0.0;
  double pre = csqrt_((2.0*j3+1.0)*cfact(j1+j2-j3)*cfact(j1-j2+j3)*cfact(-j1+j2+j3)/cfact(j1+j2+j3+1));
  pre *= csqrt_(cfact(j1+m1)*cfact(j1-m1)*cfact(j2+m2)*cfact(j2-m2)*cfact(j3+m3)*cfact(j3-m3));
  double s = 0.0;
  for (int k=0;k<=j1+j2+j3;++k){
    int d0=j1+j2-j3-k, d1=j1-m1-k, d2=j2+m2-k, d3=j3-j2+m1+k, d4=j3-j1-m2+k;
    if (d0<0||d1<0||d2<0||d3<0||d4<0) continue;
    double term = 1.0/(cfact(k)*cfact(d0)*cfact(d1)*cfact(d2)*cfact(d3)*cfact(d4));
    s += (k&1) ? -term : term;
  }
  return pre*s;
}

constexpr Cplx uent(int l,int a,int i){
  const double s = 0.70710678118654752440;
  int ma = a - l;
  if (ma==0) { if (i==l) return Cplx{1.0,0.0}; return Cplx{0.0,0.0}; }
  if (ma>0){
    int m = ma; double sg = (m&1) ? -1.0 : 1.0;
    if (i==l+m) return Cplx{sg*s, 0.0};
    if (i==l-m) return Cplx{s, 0.0};
    return Cplx{0.0,0.0};
  }
  int m = -ma; double sg = (m&1) ? -1.0 : 1.0;
  if (i==l+m) return Cplx{0.0, -sg*s};
  if (i==l-m) return Cplx{0.0, s};
  return Cplx{0.0,0.0};
}

constexpr double real_cg_entry(int l1,int l2,int l3,int a,int b,int c){
  double acc = 0.0;
  int ii0 = a, ii1 = 2*l1-a;
  int jj0 = b, jj1 = 2*l2-b;
  for (int x=0;x<2;++x){
    int i = (x==0)? ii0 : ii1;
    if (x==1 && ii1==ii0) break;
    Cplx u1 = uent(l1,a,i); if (u1.re==0.0 && u1.im==0.0) continue;
    for (int y=0;y<2;++y){
      int j = (y==0)? jj0 : jj1;
      if (y==1 && jj1==jj0) break;
      Cplx u2 = uent(l2,b,j); if (u2.re==0.0 && u2.im==0.0) continue;
      int k = (i-l1)+(j-l2)+l3;
      if (k<0 || k>2*l3) continue;
      Cplx u3 = uent(l3,c,k); if (u3.re==0.0 && u3.im==0.0) continue;
      double cg = cg_coeff(l1,i-l1,l2,j-l2,l3,k-l3);
      if (cg==0.0) continue;
      double pr = u1.re*u2.re - u1.im*u2.im;
      double pi = u1.re*u2.im + u1.im*u2.re;
      acc += (pr*u3.re + pi*u3.im) * cg;
    }
  }
  return acc;
}

struct CGT { float v[5][5][5]; };
constexpr CGT make_cg(int l1,int l2,int l3){
  CGT t{};
  for (int a=0;a<2*l1+1;++a)
    for (int b=0;b<2*l2+1;++b)
      for (int c=0;c<2*l3+1;++c)
        t.v[a][b][c] = (float)real_cg_entry(l1,l2,l3,a,b,c);
  return t;
}

// ---------------- device helpers ----------------
__device__ __forceinline__ float silu_(float x){ return x / (1.0f + __expf(-x)); }

union H16 { _Float16 h; unsigned short u; };
__device__ __forceinline__ float h2f(unsigned short u){ H16 c; c.u = u; return (float)c.h; }
__device__ __forceinline__ unsigned short f2h_u(float x){ H16 c; c.h = (_Float16)x; return c.u; }
__device__ __forceinline__ unsigned int pack2(float a, float b){
  H16 x, y; x.h = (_Float16)a; y.h = (_Float16)b;
  return ((unsigned int)y.u << 16) | x.u;
}
__device__ __forceinline__ v2f make2(float s){ v2f r; r.x = s; r.y = s; return r; }

// paired (2-edge) TP: msg[d] += rl * sum_{a,b} CG[a][b][d]*sp[a]*g[b]  (all v2f)
template<int L1,int L2,int L3>
__device__ __forceinline__ void tp_pk(const v2f* sp, const v2f* g, v2f rl, v2f* msg){
  constexpr CGT T = make_cg(L1,L2,L3);
  constexpr int NA = 2*L1+1, NB = 2*L2+1, ND = 2*L3+1;
  v2f t[ND];
#pragma unroll
  for (int d=0;d<ND;++d) t[d] = make2(0.f);
#pragma unroll
  for (int b=0;b<NB;++b){
#pragma unroll
    for (int d=0;d<ND;++d){
      v2f u = make2(0.f); bool any = false;
#pragma unroll
      for (int a=0;a<NA;++a){
        const float cg = T.v[a][b][d];
        if (cg != 0.f){ u = cg*sp[a] + u; any = true; }
      }
      if (any) t[d] = u*g[b] + t[d];
    }
  }
#pragma unroll
  for (int d=0;d<ND;++d) msg[d] = rl*t[d] + msg[d];
}

// paired (2-node) symmetric-contraction accum (v2f)
template<int L1,int L2,int L3>
__device__ __forceinline__ void sc_pk(const v2f* X, const v2f* Y, v2f w, v2f* out){
  constexpr CGT T = make_cg(L1,L2,L3);
  constexpr int NA = 2*L1+1, NB = 2*L2+1, ND = 2*L3+1;
#pragma unroll
  for (int d=0;d<ND;++d){
    v2f s = make2(0.f);
#pragma unroll
    for (int a=0;a<NA;++a){
#pragma unroll
      for (int b=0;b<NB;++b){
        const float cg = T.v[a][b][d];
        if (cg != 0.f) s = (cg*X[a])*Y[b] + s;
      }
    }
    out[d] = w*s + out[d];
  }
}

// ---------------- kernel 0: atomic-free counting sort of nodes by element ----------------
__global__ void __launch_bounds__(256) k_nodesort(const int* __restrict__ idx,
                                                  int* __restrict__ nperm){
  __shared__ int cnt[NE][257];
  __shared__ int base[NE];
  const int t = threadIdx.x;
  const int CH = 40;                      // 256*40 = 10240 >= NNODES
  int c[NE];
#pragma unroll
  for (int e=0;e<NE;++e) c[e]=0;
  int cache[CH];
  for (int i=0;i<CH;++i){
    const int n = t*CH+i;
    const int v = (n<NNODES) ? idx[n] : -1;
    cache[i] = v;
    if (v>=0) c[v]++;
  }
#pragma unroll
  for (int e=0;e<NE;++e) cnt[e][t+1] = c[e];
  if (t < NE) cnt[t][0] = 0;
  __syncthreads();
  for (int off=1; off<256; off<<=1){
    int v[NE];
#pragma unroll
    for (int e=0;e<NE;++e) v[e] = (t>=off) ? cnt[e][t-off+1] : 0;
    __syncthreads();
#pragma unroll
    for (int e=0;e<NE;++e) cnt[e][t+1] += v[e];
    __syncthreads();
  }
  if (t==0){ int run=0; for (int e=0;e<NE;++e){ base[e]=run; run += cnt[e][256]; } }
  __syncthreads();
  int cur[NE];
#pragma unroll
  for (int e=0;e<NE;++e) cur[e] = base[e] + cnt[e][t];   // exclusive prefix for this thread
  for (int i=0;i<CH;++i){
    const int v = cache[i];
    if (v>=0) nperm[cur[v]++] = t*CH+i;
  }
}

// ---------------- kernel 1: h1p = per-irrep h1 @ W_lin_in * 1/sqrt(K); zero rdeg ----------------
__global__ void __launch_bounds__(64) k_lin_in(const float* __restrict__ h1,
                                               const float* __restrict__ W,
                                               float* __restrict__ h1p,
                                               int* __restrict__ rdeg){
  const int n = blockIdx.x;
  const int d = threadIdx.x;
  if (d == 0) rdeg[n] = 0;
  const float* row = h1 + (long)n*576;
  float acc[9];
#pragma unroll
  for (int i=0;i<9;++i) acc[i] = 0.f;
  for (int c=0;c<64;++c){
    const float w0 = W[c*64 + d];
    const float w1 = W[4096 + c*64 + d];
    const float w2 = W[8192 + c*64 + d];
    acc[0] = fmaf(row[c], w0, acc[0]);
#pragma unroll
    for (int m=0;m<3;++m) acc[1+m] = fmaf(row[64+m*64+c], w1, acc[1+m]);
#pragma unroll
    for (int m=0;m<5;++m) acc[4+m] = fmaf(row[256+m*64+c], w2, acc[4+m]);
  }
  float* o = h1p + (long)n*576;
  o[d] = acc[0]*0.125f;
#pragma unroll
  for (int m=0;m<3;++m) o[64+m*64+d] = acc[1+m]*0.125f;
#pragma unroll
  for (int m=0;m<5;++m) o[256+m*64+d] = acc[4+m]*0.125f;
}

// ---------------- kernel 1b: radial MLP hidden layers + receiver histogram ----------------
__global__ void __launch_bounds__(256) k_mlp(const float* __restrict__ ele,
                                             const float* __restrict__ W0, const float* __restrict__ b0,
                                             const float* __restrict__ W1, const float* __restrict__ b1,
                                             const float* __restrict__ W2, const float* __restrict__ b2,
                                             const int* __restrict__ receiver,
                                             int* __restrict__ rdeg,
                                             float* __restrict__ hmlp){
  const int e = blockIdx.x*256 + threadIdx.x;
  if (e >= NEDGES) return;
  atomicAdd(&rdeg[receiver[e]], 1);
  float x[8];
#pragma unroll
  for (int i=0;i<8;++i) x[i] = ele[(long)e*8 + i];
  float h[32];
#pragma unroll
  for (int d=0;d<32;++d){
    float acc = b0[d];
#pragma unroll
    for (int i=0;i<8;++i) acc = fmaf(x[i], W0[i*32+d], acc);
    h[d] = silu_(acc);
  }
#pragma unroll
  for (int L=0; L<2; ++L){
    const float* Wl = L ? W2 : W1;
    const float* bl = L ? b2 : b1;
    float acc[32];
#pragma unroll
    for (int d=0;d<32;++d) acc[d] = bl[d];
    for (int j=0;j<32;++j){
      const float hj = h[j];
#pragma unroll
      for (int d=0;d<32;++d) acc[d] = fmaf(hj, Wl[j*32+d], acc[d]);
    }
#pragma unroll
    for (int d=0;d<32;++d) h[d] += silu_(acc[d]);
  }
  float* o = hmlp + (long)e*32;
#pragma unroll
  for (int d=0;d<32;++d) o[d] = h[d];
}

// ---------------- CSR scan + fill ----------------
__global__ void __launch_bounds__(256) k_scan(const int* __restrict__ deg,
                                              int* __restrict__ rowptr,
                                              int* __restrict__ cursor){
  __shared__ int sums[256];
  const int t = threadIdx.x;
  const int CH = 40;
  const int base = t*CH;
  int s = 0;
  for (int i=0;i<CH;++i){ int idx = base+i; if (idx < NNODES) s += deg[idx]; }
  sums[t] = s; __syncthreads();
  for (int off=1; off<256; off<<=1){
    int v = (t>=off) ? sums[t-off] : 0;
    __syncthreads();
    sums[t] += v;
    __syncthreads();
  }
  int run = (t==0) ? 0 : sums[t-1];
  for (int i=0;i<CH;++i){
    int idx = base+i;
    if (idx < NNODES){ rowptr[idx] = run; cursor[idx] = run; run += deg[idx]; }
  }
  if (t==255) rowptr[NNODES] = sums[255];
}

__global__ void __launch_bounds__(256) k_fill_pos(const int* __restrict__ receiver,
                                                  int* __restrict__ cursor,
                                                  int* __restrict__ epos){
  const int e = blockIdx.x*256 + threadIdx.x;
  if (e < NEDGES) epos[e] = atomicAdd(&cursor[receiver[e]], 1);
}

// ---------------- kernel 2: edge kernel, 8 edges/wave as 4 pairs, W3 staged in LDS (f16) ----------------
// W3 (90 KB f32) does not fit L1, so the previous 352 dword loads/wave were all ~200-cyc
// L2 round-trips -- the dominant stall. Stage once per BLOCK as f16 [j][lane][12] (48 KB);
// the rl GEMM then reads per-lane contiguous 24B via 3x ds_read_b64 per j (low latency).
__global__ void __launch_bounds__(256) k_edge_pk(const int* __restrict__ sender,
                                             const int* __restrict__ epos,
                                             const float* __restrict__ hmlp,
                                             const float* __restrict__ sph,
                                             const float* __restrict__ h1p,
                                             const float* __restrict__ W3, const float* __restrict__ b3,
                                             unsigned int* __restrict__ msg){
  __shared__ unsigned short W3s[32][64][12];   // 48 KB f16, block-shared
  __shared__ float sps[4][72];                 // [a][8] per wave
  const int wid  = threadIdx.x >> 6;
  const int lane = threadIdx.x & 63;
  const int ubase = __builtin_amdgcn_readfirstlane((blockIdx.x*4 + wid) * 8);

  // cooperative W3 stage: coalesced f32 reads -> f16 LDS writes
  for (int idx = threadIdx.x; idx < 704*32; idx += 256){
    const int j = idx / 704;
    const int r = idx - j*704;
    const int p = r >> 6, c = r & 63;
    W3s[j][c][p] = f2h_u(W3[idx]);
  }

  {
    const int idx = lane;                       // 0..63
    const int e = idx/9, a = idx - 9*e;
    sps[wid][a*8 + e] = sph[(long)ubase*9 + idx];
  }
  if (lane < 8){
    const int idx = 64 + lane;                  // 64..71
    const int e = idx/9, a = idx - 9*e;
    sps[wid][a*8 + e] = sph[(long)ubase*9 + idx];
  }

  int sidx[8], pos[8];
#pragma unroll
  for (int e=0;e<8;++e){ sidx[e] = sender[ubase+e]; pos[e] = epos[ubase+e]; }

  // gather sender features as pairs (issued early; latency hidden by rl GEMM)
  v2f g2[4][9];
#pragma unroll
  for (int q=0;q<4;++q){
    const float* hp0 = h1p + (long)sidx[2*q]  *576;
    const float* hp1 = h1p + (long)sidx[2*q+1]*576;
#pragma unroll
    for (int i=0;i<9;++i){ g2[q][i].x = hp0[i*64+lane]; g2[q][i].y = hp1[i*64+lane]; }
  }

  const float* hu = hmlp + (long)ubase*32;   // wave-uniform -> s_load

  __syncthreads();   // W3s ready
  __builtin_amdgcn_s_setprio(1);

  // rl GEMM (paired): rl2[p][q] += h2{e0,e1} * w3v[p] (splat from LDS f16)
  v2f rl2[11][4];
#pragma unroll
  for (int p=0;p<11;++p){
    const float bb = b3[p*64+lane];
#pragma unroll
    for (int q=0;q<4;++q) rl2[p][q] = make2(bb);
  }
  for (int jb=0;jb<32;jb+=4){
    float w3v[4][11];
#pragma unroll
    for (int jj=0;jj<4;++jj){
      const u16x4 lo = *(const u16x4*)&W3s[jb+jj][lane][0];
      const u16x4 md = *(const u16x4*)&W3s[jb+jj][lane][4];
      const u16x4 hi = *(const u16x4*)&W3s[jb+jj][lane][8];
#pragma unroll
      for (int p=0;p<4;++p)  w3v[jj][p]   = h2f(lo[p]);
#pragma unroll
      for (int p=0;p<4;++p)  w3v[jj][4+p] = h2f(md[p]);
#pragma unroll
      for (int p=0;p<3;++p)  w3v[jj][8+p] = h2f(hi[p]);
    }
#pragma unroll
    for (int q=0;q<4;++q){
#pragma unroll
      for (int jj=0;jj<4;++jj){
        v2f h2; h2.x = hu[(2*q)*32 + jb + jj]; h2.y = hu[(2*q+1)*32 + jb + jj];
#pragma unroll
        for (int p=0;p<11;++p) rl2[p][q] = h2*w3v[jj][p] + rl2[p][q];
      }
    }
  }

  // TP (paired) + packed f16 store at CSR positions
#pragma unroll
  for (int q=0;q<4;++q){
    v2f sp2[9];
#pragma unroll
    for (int a=0;a<9;++a) sp2[a] = *(const v2f*)&sps[wid][a*8 + 2*q];
    v2f m0[1]; m0[0] = make2(0.f);
    v2f m1[3]; m1[0]=m1[1]=m1[2]=make2(0.f);
    v2f m2[5]; m2[0]=m2[1]=m2[2]=m2[3]=m2[4]=make2(0.f);
    tp_pk<0,0,0>(sp2+0, &g2[q][0], rl2[0][q],  m0);
    tp_pk<0,1,1>(sp2+0, &g2[q][1], rl2[1][q],  m1);
    tp_pk<0,2,2>(sp2+0, &g2[q][4], rl2[2][q],  m2);
    tp_pk<1,0,1>(sp2+1, &g2[q][0], rl2[3][q],  m1);
    tp_pk<1,1,0>(sp2+1, &g2[q][1], rl2[4][q],  m0);
    tp_pk<1,1,2>(sp2+1, &g2[q][1], rl2[5][q],  m2);
    tp_pk<1,2,1>(sp2+1, &g2[q][4], rl2[6][q],  m1);
    tp_pk<2,0,2>(sp2+4, &g2[q][0], rl2[7][q],  m2);
    tp_pk<2,1,1>(sp2+4, &g2[q][1], rl2[8][q],  m1);
    tp_pk<2,2,0>(sp2+4, &g2[q][4], rl2[9][q],  m0);
    tp_pk<2,2,2>(sp2+4, &g2[q][4], rl2[10][q], m2);
    {
      unsigned int pk[5];
      pk[0] = pack2(m0[0].x, m1[0].x);
      pk[1] = pack2(m1[1].x, m1[2].x);
      pk[2] = pack2(m2[0].x, m2[1].x);
      pk[3] = pack2(m2[2].x, m2[3].x);
      pk[4] = pack2(m2[4].x, 0.f);
      unsigned int* mp = msg + (size_t)pos[2*q]*320;
#pragma unroll
      for (int k=0;k<5;++k) mp[k*64 + lane] = pk[k];
    }
    {
      unsigned int pk[5];
      pk[0] = pack2(m0[0].y, m1[0].y);
      pk[1] = pack2(m1[1].y, m1[2].y);
      pk[2] = pack2(m2[0].y, m2[1].y);
      pk[3] = pack2(m2[2].y, m2[3].y);
      pk[4] = pack2(m2[4].y, 0.f);
      unsigned int* mp = msg + (size_t)pos[2*q+1]*320;
#pragma unroll
      for (int k=0;k<5;++k) mp[k*64 + lane] = pk[k];
    }
  }
  __builtin_amdgcn_s_setprio(0);
}

// ---------------- kernel 3: node kernel, TWO nodes per wave (element-paired, v2f) ----------------
__global__ void __launch_bounds__(256) k_node_p(const int* __restrict__ indices,
                                             const int* __restrict__ nperm,
                                             const float* __restrict__ h1,
                                             const int* __restrict__ rowptr,
                                             const unsigned int* __restrict__ msg,
                                             const float* __restrict__ Wmix,
                                             const float* __restrict__ w1,
                                             const float* __restrict__ w2,
                                             const float* __restrict__ w3,
                                             const float* __restrict__ Wom,
                                             const float* __restrict__ Woh,
                                             float* __restrict__ out){
  __shared__ float S[4][9][64][2];
  __shared__ float Bb[4][4][64][2];
  const int wid  = threadIdx.x >> 6;
  const int lane = threadIdx.x & 63;
  const int p0 = (blockIdx.x*4 + wid)*2;
  const int n0 = __builtin_amdgcn_readfirstlane(nperm[p0]);
  const int n1 = __builtin_amdgcn_readfirstlane(nperm[p0+1]);
  const int e0 = __builtin_amdgcn_readfirstlane(indices[n0]);
  const int e1 = __builtin_amdgcn_readfirstlane(indices[n1]);

  // phase 1: gather-sum incoming messages for both nodes (lane = channel c)
#pragma unroll
  for (int k2=0;k2<2;++k2){
    const int nk = k2 ? n1 : n0;
    const int start = rowptr[nk], end = rowptr[nk+1];
    float A[9];
#pragma unroll
    for (int i=0;i<9;++i) A[i] = 0.f;
    for (int q=start; q<end; ++q){
      const unsigned int* mp = msg + (size_t)q*320;
#pragma unroll
      for (int k=0;k<5;++k){
        const unsigned int v = mp[k*64 + lane];
        A[2*k] += h2f((unsigned short)(v & 0xffff));
        if (2*k+1 < 9) A[2*k+1] += h2f((unsigned short)(v >> 16));
      }
    }
#pragma unroll
    for (int i=0;i<9;++i) S[wid][i][lane][k2] = A[i];
  }

  // phase 2: Amix (lane = output channel d); weight loads shared when e0==e1
  v2f ax[9];
#pragma unroll
  for (int i=0;i<9;++i) ax[i] = make2(0.f);
  if (e0 == e1){
    const float* Wm0 = Wmix + (size_t)(0*NE + e0)*4096;
    const float* Wm1 = Wmix + (size_t)(1*NE + e0)*4096;
    const float* Wm2 = Wmix + (size_t)(2*NE + e0)*4096;
    for (int c=0;c<64;++c){
      const float wv0 = Wm0[c*64+lane];
      const float wv1 = Wm1[c*64+lane];
      const float wv2 = Wm2[c*64+lane];
      ax[0] = (*(const v2f*)&S[wid][0][c][0])*wv0 + ax[0];
#pragma unroll
      for (int m=0;m<3;++m) ax[1+m] = (*(const v2f*)&S[wid][1+m][c][0])*wv1 + ax[1+m];
#pragma unroll
      for (int m=0;m<5;++m) ax[4+m] = (*(const v2f*)&S[wid][4+m][c][0])*wv2 + ax[4+m];
    }
  } else {
    const float* Wm0a = Wmix + (size_t)(0*NE + e0)*4096;
    const float* Wm1a = Wmix + (size_t)(1*NE + e0)*4096;
    const float* Wm2a = Wmix + (size_t)(2*NE + e0)*4096;
    const float* Wm0b = Wmix + (size_t)(0*NE + e1)*4096;
    const float* Wm1b = Wmix + (size_t)(1*NE + e1)*4096;
    const float* Wm2b = Wmix + (size_t)(2*NE + e1)*4096;
    for (int c=0;c<64;++c){
      v2f wv0; wv0.x = Wm0a[c*64+lane]; wv0.y = Wm0b[c*64+lane];
      v2f wv1; wv1.x = Wm1a[c*64+lane]; wv1.y = Wm1b[c*64+lane];
      v2f wv2; wv2.x = Wm2a[c*64+lane]; wv2.y = Wm2b[c*64+lane];
      ax[0] = (*(const v2f*)&S[wid][0][c][0])*wv0 + ax[0];
#pragma unroll
      for (int m=0;m<3;++m) ax[1+m] = (*(const v2f*)&S[wid][1+m][c][0])*wv1 + ax[1+m];
#pragma unroll
      for (int m=0;m<5;++m) ax[4+m] = (*(const v2f*)&S[wid][4+m][c][0])*wv2 + ax[4+m];
    }
  }
#pragma unroll
  for (int i=0;i<9;++i) ax[i] = ax[i]*0.0039528470752104741f;  // (1/AVG_NEIGH)*MIX_NORM

  // phase 3: symmetric contraction, lane-local, paired
  const v2f* amix0 = ax;
  const v2f* amix1 = ax+1;
  const v2f* amix2 = ax+4;
  v2f w2n[5], w3n[5];
#pragma unroll
  for (int p=0;p<5;++p){
    w2n[p].x = w2[(size_t)(e0*5+p)*64 + lane];
    w2n[p].y = w2[(size_t)(e1*5+p)*64 + lane];
    w3n[p].x = w3[(size_t)(e0*5+p)*64 + lane];
    w3n[p].y = w3[(size_t)(e1*5+p)*64 + lane];
  }
  v2f t20[1]; t20[0] = make2(0.f);
  v2f t21[3]; t21[0]=t21[1]=t21[2]=make2(0.f);
  sc_pk<0,0,0>(amix0, amix0, w2n[0], t20);
  sc_pk<1,1,0>(amix1, amix1, w2n[1], t20);
  sc_pk<2,2,0>(amix2, amix2, w2n[2], t20);
  sc_pk<0,1,1>(amix0, amix1, w2n[3], t21);
  sc_pk<1,2,1>(amix1, amix2, w2n[4], t21);
  v2f t30[1]; t30[0] = make2(0.f);
  v2f t31[3]; t31[0]=t31[1]=t31[2]=make2(0.f);
  sc_pk<0,0,0>(t20, amix0, w3n[0], t30);
  sc_pk<1,1,0>(t21, amix1, w3n[1], t30);
  sc_pk<0,1,1>(t20, amix1, w3n[2], t31);
  sc_pk<1,0,1>(t21, amix0, w3n[3], t31);
  sc_pk<1,2,1>(t21, amix2, w3n[4], t31);

  v2f w1_0, w1_1;
  w1_0.x = w1[(size_t)(e0*2+0)*64 + lane];
  w1_0.y = w1[(size_t)(e1*2+0)*64 + lane];
  w1_1.x = w1[(size_t)(e0*2+1)*64 + lane];
  w1_1.y = w1[(size_t)(e1*2+1)*64 + lane];
  *(v2f*)&Bb[wid][0][lane][0] = w1_0*amix0[0] + (t20[0] + t30[0]);
#pragma unroll
  for (int m=0;m<3;++m)
    *(v2f*)&Bb[wid][1+m][lane][0] = w1_1*amix1[m] + (t21[m] + t31[m]);

  // phase 4: stage the 4 needed h1 rows for both nodes (same wave finished with S)
  {
    const float* hr0 = h1 + (long)n0*576;
    const float* hr1 = h1 + (long)n1*576;
#pragma unroll
    for (int r=0;r<4;++r){
      S[wid][r][lane][0] = hr0[r*64 + lane];
      S[wid][r][lane][1] = hr1[r*64 + lane];
    }
  }

  // phase 5: output linears (lane = d); Woh/Wom are element-independent -> always shared
  v2f o[4];
#pragma unroll
  for (int i=0;i<4;++i) o[i] = make2(0.f);
  for (int c=0;c<64;++c){
    const float wh0 = Woh[c*64+lane];
    const float wh1 = Woh[4096 + c*64+lane];
    const float wm0 = Wom[c*64+lane];
    const float wm1 = Wom[4096 + c*64+lane];
    o[0] = (*(const v2f*)&S[wid][0][c][0])*wh0 + o[0];
    o[0] = (*(const v2f*)&Bb[wid][0][c][0])*wm0 + o[0];
#pragma unroll
    for (int m=0;m<3;++m){
      o[1+m] = (*(const v2f*)&S[wid][1+m][c][0])*wh1 + o[1+m];
      o[1+m] = (*(const v2f*)&Bb[wid][1+m][c][0])*wm1 + o[1+m];
    }
  }
  float* or0 = out + (long)n0*256;
  float* or1 = out + (long)n1*256;
  or0[lane] = o[0].x*0.125f;
  or1[lane] = o[0].y*0.125f;
#pragma unroll
  for (int m=0;m<3;++m){
    or0[64+m*64+lane] = o[1+m].x*0.125f;
    or1[64+m*64+lane] = o[1+m].y*0.125f;
  }
}

// ---------------- launch ----------------
extern "C" void kernel_launch(void* const* d_in, const int* in_sizes, int n_in,
                              void* d_out, int out_size, void* d_ws, size_t ws_size,
                              hipStream_t stream){
  const int*   sender   = (const int*)  d_in[0];
  const int*   receiver = (const int*)  d_in[1];
  const int*   indices  = (const int*)  d_in[2];
  const float* node_feat= (const float*)d_in[4];
  const float* ele      = (const float*)d_in[5];
  const float* sph      = (const float*)d_in[6];
  const float* W_lin    = (const float*)d_in[7];
  const float* W0 = (const float*)d_in[8],  *b0 = (const float*)d_in[9];
  const float* W1 = (const float*)d_in[10], *b1 = (const float*)d_in[11];
  const float* W2 = (const float*)d_in[12], *b2 = (const float*)d_in[13];
  const float* W3 = (const float*)d_in[14], *b3 = (const float*)d_in[15];
  const float* Wmix = (const float*)d_in[16];
  const float* w1 = (const float*)d_in[17];
  const float* w2 = (const float*)d_in[18];
  const float* w3 = (const float*)d_in[19];
  const float* Wom = (const float*)d_in[20];
  const float* Woh = (const float*)d_in[21];
  float* out = (float*)d_out;

  char* ws = (char*)d_ws;
  const size_t OFF_H1P  = 0;                                 // 23,040,000
  const size_t OFF_HMLP = OFF_H1P  + (size_t)NNODES*576*4;   // +12,800,000
  const size_t OFF_MSG  = OFF_HMLP + (size_t)NEDGES*32*4;    // +128,000,000
  const size_t OFF_RDEG = OFF_MSG  + (size_t)NEDGES*320*4;
  const size_t OFF_RROW = OFF_RDEG + 40960;
  const size_t OFF_RCUR = OFF_RROW + 40964;
  const size_t OFF_EPOS = OFF_RCUR + 40960;
  const size_t OFF_NPRM = OFF_EPOS + (size_t)NEDGES*4;

  float* h1p  = (float*)(ws + OFF_H1P);
  float* hmlp = (float*)(ws + OFF_HMLP);
  unsigned int* msg = (unsigned int*)(ws + OFF_MSG);
  int* rdeg   = (int*)(ws + OFF_RDEG);
  int* rrow   = (int*)(ws + OFF_RROW);
  int* rcur   = (int*)(ws + OFF_RCUR);
  int* epos   = (int*)(ws + OFF_EPOS);
  int* nperm  = (int*)(ws + OFF_NPRM);

  k_nodesort<<<1, 256, 0, stream>>>(indices, nperm);
  k_lin_in<<<NNODES, 64, 0, stream>>>(node_feat, W_lin, h1p, rdeg);
  k_mlp<<<(NEDGES+255)/256, 256, 0, stream>>>(ele, W0,b0,W1,b1,W2,b2,
                                              receiver, rdeg, hmlp);
  k_scan<<<1, 256, 0, stream>>>(rdeg, rrow, rcur);
  k_fill_pos<<<(NEDGES+255)/256, 256, 0, stream>>>(receiver, rcur, epos);
  k_edge_pk<<<NEDGES/32, 256, 0, stream>>>(sender, epos, hmlp, sph, h1p, W3, b3, msg);
  k_node_p<<<NNODES/8, 256, 0, stream>>>(indices, nperm, node_feat, rrow, msg,
                                         Wmix, w1, w2, w3, Wom, Woh, out);
}

// Round 16
// 257.091 us; speedup vs baseline: 1.1005x; 1.1005x over previous
//
#include <hip/hip_runtime.h>
#include <math.h>

#define NNODES 10000
#define NEDGES 100000

typedef float v2f __attribute__((ext_vector_type(2)));

// ---------------- compile-time Clebsch-Gordan (port of reference) ----------------
struct Cplx { double re, im; };

constexpr double cfact(int n){ double r=1.0; for(int i=2;i<=n;++i) r*=i; return r; }

constexpr double csqrt_(double x){
  if (x<=0.0) return 0.0;
  double g = x<1.0 ? 1.0 : x;
  for (int it=0; it<64; ++it){ double ng = 0.5*(g + x/g); if (ng==g) break; g = ng; }
  return g;
}

constexpr double cg_coeff(int j1,int m1,int j2,int m2,int j3,int m3){
  if (m1+m2!=m3) return 0.0;
  int lo = j1>j2 ? j1-j2 : j2-j1;
  if (j3<lo || j3>j1+j2) return 0.0;
  if (m1<-j1||m1>j1||m2<-j2||m2>j2||m3<-j3||m3>j3) return 0.0;
  double pre = csqrt_((2.0*j3+1.0)*cfact(j1+j2-j3)*cfact(j1-j2+j3)*cfact(-j1+j2+j3)/cfact(j1+j2+j3+1));
  pre *= csqrt_(cfact(j1+m1)*cfact(j1-m1)*cfact(j2+m2)*cfact(j2-m2)*cfact(j3+m3)*cfact(j3-m3));
  double s = 0.0;
  for (int k=0;k<=j1+j2+j3;++k){
    int d0=j1+j2-j3-k, d1=j1-m1-k, d2=j2+m2-k, d3=j3-j2+m1+k, d4=j3-j1-m2+k;
    if (d0<0||d1<0||d2<0||d3<0||d4<0) continue;
    double term = 1.0/(cfact(k)*cfact(d0)*cfact(d1)*cfact(d2)*cfact(d3)*cfact(d4));
    s += (k&1) ? -term : term;
  }
  return pre*s;
}

constexpr Cplx uent(int l,int a,int i){
  const double s = 0.70710678118654752440;
  int ma = a - l;
  if (ma==0) { if (i==l) return Cplx{1.0,0.0}; return Cplx{0.0,0.0}; }
  if (ma>0){
    int m = ma; double sg = (m&1) ? -1.0 : 1.0;
    if (i==l+m) return Cplx{sg*s, 0.0};
    if (i==l-m) return Cplx{s, 0.0};
    return Cplx{0.0,0.0};
  }
  int m = -ma; double sg = (m&1) ? -1.0 : 1.0;
  if (i==l+m) return Cplx{0.0, -sg*s};
  if (i==l-m) return Cplx{0.0, s};
  return Cplx{0.0,0.0};
}

constexpr double real_cg_entry(int l1,int l2,int l3,int a,int b,int c){
  double acc = 0.0;
  int ii0 = a, ii1 = 2*l1-a;
  int jj0 = b, jj1 = 2*l2-b;
  for (int x=0;x<2;++x){
    int i = (x==0)? ii0 : ii1;
    if (x==1 && ii1==ii0) break;
    Cplx u1 = uent(l1,a,i); if (u1.re==0.0 && u1.im==0.0) continue;
    for (int y=0;y<2;++y){
      int j = (y==0)? jj0 : jj1;
      if (y==1 && jj1==jj0) break;
      Cplx u2 = uent(l2,b,j); if (u2.re==0.0 && u2.im==0.0) continue;
      int k = (i-l1)+(j-l2)+l3;
      if (k<0 || k>2*l3) continue;
      Cplx u3 = uent(l3,c,k); if (u3.re==0.0 && u3.im==0.0) continue;
      double cg = cg_coeff(l1,i-l1,l2,j-l2,l3,k-l3);
      if (cg==0.0) continue;
      double pr = u1.re*u2.re - u1.im*u2.im;
      double pi = u1.re*u2.im + u1.im*u2.re;
      acc += (pr*u3.re + pi*u3.im) * cg;
    }
  }
  return acc;
}

struct CGT { float v[5][5][5]; };
constexpr CGT make_cg(int l1,int l2,int l3){
  CGT t{};
  for (int a=0;a<2*l1+1;++a)
    for (int b=0;b<2*l2+1;++b)
      for (int c=0;c<2*l3+1;++c)
        t.v[a][b][c] = (float)real_cg_entry(l1,l2,l3,a,b,c);
  return t;
}

// ---------------- device helpers ----------------
__device__ __forceinline__ float silu_(float x){ return x / (1.0f + __expf(-x)); }

union H16 { _Float16 h; unsigned short u; };
__device__ __forceinline__ float h2f(unsigned short u){ H16 c; c.u = u; return (float)c.h; }
__device__ __forceinline__ unsigned int pack2(float a, float b){
  H16 x, y; x.h = (_Float16)a; y.h = (_Float16)b;
  return ((unsigned int)y.u << 16) | x.u;
}
__device__ __forceinline__ v2f make2(float s){ v2f r; r.x = s; r.y = s; return r; }

// paired (2-edge) TP: msg[d] += rl * sum_{a,b} CG[a][b][d]*sp[a]*g[b]  (all v2f)
template<int L1,int L2,int L3>
__device__ __forceinline__ void tp_pk(const v2f* sp, const v2f* g, v2f rl, v2f* msg){
  constexpr CGT T = make_cg(L1,L2,L3);
  constexpr int NA = 2*L1+1, NB = 2*L2+1, ND = 2*L3+1;
  v2f t[ND];
#pragma unroll
  for (int d=0;d<ND;++d) t[d] = make2(0.f);
#pragma unroll
  for (int b=0;b<NB;++b){
#pragma unroll
    for (int d=0;d<ND;++d){
      v2f u = make2(0.f); bool any = false;
#pragma unroll
      for (int a=0;a<NA;++a){
        const float cg = T.v[a][b][d];
        if (cg != 0.f){ u = cg*sp[a] + u; any = true; }
      }
      if (any) t[d] = u*g[b] + t[d];
    }
  }
#pragma unroll
  for (int d=0;d<ND;++d) msg[d] = rl*t[d] + msg[d];
}

template<int L1,int L2,int L3>
__device__ __forceinline__ void sc_accum(const float* X, const float* Y, float w, float* out){
  constexpr CGT T = make_cg(L1,L2,L3);
  constexpr int NA = 2*L1+1, NB = 2*L2+1, ND = 2*L3+1;
#pragma unroll
  for (int d=0;d<ND;++d){
    float s = 0.f;
#pragma unroll
    for (int a=0;a<NA;++a){
#pragma unroll
      for (int b=0;b<NB;++b){
        const float cg = T.v[a][b][d];
        if (cg != 0.f) s = fmaf(cg*X[a], Y[b], s);
      }
    }
    out[d] = fmaf(w, s, out[d]);
  }
}

// ---------------- kernel 1: h1p = per-irrep h1 @ W_lin_in * 1/sqrt(K); zero deg ----------------
__global__ void __launch_bounds__(64) k_lin_in(const float* __restrict__ h1,
                                               const float* __restrict__ W,
                                               float* __restrict__ h1p,
                                               int* __restrict__ deg){
  const int n = blockIdx.x;
  const int d = threadIdx.x;
  if (d == 0) deg[n] = 0;
  const float* row = h1 + (long)n*576;
  float acc[9];
#pragma unroll
  for (int i=0;i<9;++i) acc[i] = 0.f;
  for (int c=0;c<64;++c){
    const float w0 = W[c*64 + d];
    const float w1 = W[4096 + c*64 + d];
    const float w2 = W[8192 + c*64 + d];
    acc[0] = fmaf(row[c], w0, acc[0]);
#pragma unroll
    for (int m=0;m<3;++m) acc[1+m] = fmaf(row[64+m*64+c], w1, acc[1+m]);
#pragma unroll
    for (int m=0;m<5;++m) acc[4+m] = fmaf(row[256+m*64+c], w2, acc[4+m]);
  }
  float* o = h1p + (long)n*576;
  o[d] = acc[0]*0.125f;
#pragma unroll
  for (int m=0;m<3;++m) o[64+m*64+d] = acc[1+m]*0.125f;
#pragma unroll
  for (int m=0;m<5;++m) o[256+m*64+d] = acc[4+m]*0.125f;
}

// ---------------- kernel 1b: radial MLP hidden layers, lane = edge ----------------
__global__ void __launch_bounds__(256) k_mlp(const float* __restrict__ ele,
                                             const float* __restrict__ W0, const float* __restrict__ b0,
                                             const float* __restrict__ W1, const float* __restrict__ b1,
                                             const float* __restrict__ W2, const float* __restrict__ b2,
                                             float* __restrict__ hmlp){
  const int e = blockIdx.x*256 + threadIdx.x;
  if (e >= NEDGES) return;
  float x[8];
#pragma unroll
  for (int i=0;i<8;++i) x[i] = ele[(long)e*8 + i];
  float h[32];
#pragma unroll
  for (int d=0;d<32;++d){
    float acc = b0[d];
#pragma unroll
    for (int i=0;i<8;++i) acc = fmaf(x[i], W0[i*32+d], acc);
    h[d] = silu_(acc);
  }
#pragma unroll
  for (int L=0; L<2; ++L){
    const float* Wl = L ? W2 : W1;
    const float* bl = L ? b2 : b1;
    float acc[32];
#pragma unroll
    for (int d=0;d<32;++d) acc[d] = bl[d];
    for (int j=0;j<32;++j){
      const float hj = h[j];
#pragma unroll
      for (int d=0;d<32;++d) acc[d] = fmaf(hj, Wl[j*32+d], acc[d]);
    }
#pragma unroll
    for (int d=0;d<32;++d) h[d] += silu_(acc[d]);
  }
  float* o = hmlp + (long)e*32;
#pragma unroll
  for (int d=0;d<32;++d) o[d] = h[d];
}

// ---------------- CSR build kernels ----------------
__global__ void __launch_bounds__(256) k_hist(const int* __restrict__ receiver, int* __restrict__ deg){
  const int e = blockIdx.x*256 + threadIdx.x;
  if (e < NEDGES) atomicAdd(&deg[receiver[e]], 1);
}

__global__ void __launch_bounds__(256) k_scan(const int* __restrict__ deg,
                                              int* __restrict__ rowptr,
                                              int* __restrict__ cursor){
  __shared__ int sums[256];
  const int t = threadIdx.x;
  const int CH = 40;
  const int base = t*CH;
  int s = 0;
  for (int i=0;i<CH;++i){ int idx = base+i; if (idx < NNODES) s += deg[idx]; }
  sums[t] = s; __syncthreads();
  for (int off=1; off<256; off<<=1){
    int v = (t>=off) ? sums[t-off] : 0;
    __syncthreads();
    sums[t] += v;
    __syncthreads();
  }
  int run = (t==0) ? 0 : sums[t-1];
  for (int i=0;i<CH;++i){
    int idx = base+i;
    if (idx < NNODES){ rowptr[idx] = run; cursor[idx] = run; run += deg[idx]; }
  }
  if (t==255) rowptr[NNODES] = sums[255];
}

__global__ void __launch_bounds__(256) k_fill_pos(const int* __restrict__ receiver,
                                                  int* __restrict__ cursor,
                                                  int* __restrict__ epos){
  const int e = blockIdx.x*256 + threadIdx.x;
  if (e < NEDGES) epos[e] = atomicAdd(&cursor[receiver[e]], 1);
}

// ---------------- kernel 2: edge kernel, 8 edges/wave as 4 pairs, packed fp32 math ----------------
// rl-GEMM and TP run on v2f (edge pairs) -> v_pk_fma_f32: 2 fma/inst.
// sph staged TRANSPOSED [a][8] in LDS so a pair's sp is one ds_read_b64.
// msg written at CSR position (receiver-sorted), packed f16 pairs [pos][5][64] uints.
__global__ void __launch_bounds__(256) k_edge_pk(const int* __restrict__ sender,
                                             const int* __restrict__ epos,
                                             const float* __restrict__ hmlp,
                                             const float* __restrict__ sph,
                                             const float* __restrict__ h1p,
                                             const float* __restrict__ W3, const float* __restrict__ b3,
                                             unsigned int* __restrict__ msg){
  __shared__ float sps[4][72];   // [a][8] per wave
  const int wid  = threadIdx.x >> 6;
  const int lane = threadIdx.x & 63;
  const int ubase = __builtin_amdgcn_readfirstlane((blockIdx.x*4 + wid) * 8);

  {
    const int idx = lane;                       // 0..63
    const int e = idx/9, a = idx - 9*e;
    sps[wid][a*8 + e] = sph[(long)ubase*9 + idx];
  }
  if (lane < 8){
    const int idx = 64 + lane;                  // 64..71
    const int e = idx/9, a = idx - 9*e;
    sps[wid][a*8 + e] = sph[(long)ubase*9 + idx];
  }

  int sidx[8], pos[8];
#pragma unroll
  for (int e=0;e<8;++e){ sidx[e] = sender[ubase+e]; pos[e] = epos[ubase+e]; }

  // gather sender features as pairs (issued early; latency hidden by rl GEMM)
  v2f g2[4][9];
#pragma unroll
  for (int q=0;q<4;++q){
    const float* hp0 = h1p + (long)sidx[2*q]  *576;
    const float* hp1 = h1p + (long)sidx[2*q+1]*576;
#pragma unroll
    for (int i=0;i<9;++i){ g2[q][i].x = hp0[i*64+lane]; g2[q][i].y = hp1[i*64+lane]; }
  }
#pragma unroll
  for (int q=0;q<4;++q)
#pragma unroll
    for (int i=0;i<9;++i) asm volatile("" : "+v"(g2[q][i]));

  const float* hu = hmlp + (long)ubase*32;   // wave-uniform -> s_load

  // rl GEMM (paired): rl2[p][q] += h2{e0,e1} * w3v[p] (splat)
  v2f rl2[11][4];
#pragma unroll
  for (int p=0;p<11;++p){
    const float bb = b3[p*64+lane];
#pragma unroll
    for (int q=0;q<4;++q) rl2[p][q] = make2(bb);
  }
  for (int jb=0;jb<32;jb+=4){
    float w3v[4][11];
#pragma unroll
    for (int jj=0;jj<4;++jj)
#pragma unroll
      for (int p=0;p<11;++p)
        w3v[jj][p] = W3[(jb+jj)*704 + p*64 + lane];
#pragma unroll
    for (int q=0;q<4;++q){
#pragma unroll
      for (int jj=0;jj<4;++jj){
        v2f h2; h2.x = hu[(2*q)*32 + jb + jj]; h2.y = hu[(2*q+1)*32 + jb + jj];
#pragma unroll
        for (int p=0;p<11;++p) rl2[p][q] = h2*w3v[jj][p] + rl2[p][q];
      }
    }
  }

  // TP (paired) + packed f16 store at CSR positions
#pragma unroll
  for (int q=0;q<4;++q){
    v2f sp2[9];
#pragma unroll
    for (int a=0;a<9;++a) sp2[a] = *(const v2f*)&sps[wid][a*8 + 2*q];
    v2f m0[1]; m0[0] = make2(0.f);
    v2f m1[3]; m1[0]=m1[1]=m1[2]=make2(0.f);
    v2f m2[5]; m2[0]=m2[1]=m2[2]=m2[3]=m2[4]=make2(0.f);
    tp_pk<0,0,0>(sp2+0, &g2[q][0], rl2[0][q],  m0);
    tp_pk<0,1,1>(sp2+0, &g2[q][1], rl2[1][q],  m1);
    tp_pk<0,2,2>(sp2+0, &g2[q][4], rl2[2][q],  m2);
    tp_pk<1,0,1>(sp2+1, &g2[q][0], rl2[3][q],  m1);
    tp_pk<1,1,0>(sp2+1, &g2[q][1], rl2[4][q],  m0);
    tp_pk<1,1,2>(sp2+1, &g2[q][1], rl2[5][q],  m2);
    tp_pk<1,2,1>(sp2+1, &g2[q][4], rl2[6][q],  m1);
    tp_pk<2,0,2>(sp2+4, &g2[q][0], rl2[7][q],  m2);
    tp_pk<2,1,1>(sp2+4, &g2[q][1], rl2[8][q],  m1);
    tp_pk<2,2,0>(sp2+4, &g2[q][4], rl2[9][q],  m0);
    tp_pk<2,2,2>(sp2+4, &g2[q][4], rl2[10][q], m2);
    // edge 2q (x half)
    {
      unsigned int pk[5];
      pk[0] = pack2(m0[0].x, m1[0].x);
      pk[1] = pack2(m1[1].x, m1[2].x);
      pk[2] = pack2(m2[0].x, m2[1].x);
      pk[3] = pack2(m2[2].x, m2[3].x);
      pk[4] = pack2(m2[4].x, 0.f);
      unsigned int* mp = msg + (size_t)pos[2*q]*320;
#pragma unroll
      for (int k=0;k<5;++k) mp[k*64 + lane] = pk[k];
    }
    // edge 2q+1 (y half)
    {
      unsigned int pk[5];
      pk[0] = pack2(m0[0].y, m1[0].y);
      pk[1] = pack2(m1[1].y, m1[2].y);
      pk[2] = pack2(m2[0].y, m2[1].y);
      pk[3] = pack2(m2[2].y, m2[3].y);
      pk[4] = pack2(m2[4].y, 0.f);
      unsigned int* mp = msg + (size_t)pos[2*q+1]*320;
#pragma unroll
      for (int k=0;k<5;++k) mp[k*64 + lane] = pk[k];
    }
  }
}

// ---------------- kernel 3: node kernel, 1 wave/node, contiguous CSR message read ----------------
__global__ void __launch_bounds__(256) k_node_c(const int* __restrict__ indices,
                                             const float* __restrict__ h1,
                                             const int* __restrict__ rowptr,
                                             const unsigned int* __restrict__ msg,
                                             const float* __restrict__ Wmix,
                                             const float* __restrict__ w1,
                                             const float* __restrict__ w2,
                                             const float* __restrict__ w3,
                                             const float* __restrict__ Wom,
                                             const float* __restrict__ Woh,
                                             float* __restrict__ out){
  __shared__ float S[4][9][64];
  __shared__ float Bb[4][4][64];
  const int wid  = threadIdx.x >> 6;
  const int lane = threadIdx.x & 63;
  const int n = blockIdx.x*4 + wid;
  const int e = __builtin_amdgcn_readfirstlane(indices[n]);

  // phase 1: contiguous gather-sum of incoming messages (lane = channel c) -> LDS
  {
    const int start = rowptr[n], end = rowptr[n+1];
    float A[9];
#pragma unroll
    for (int i=0;i<9;++i) A[i] = 0.f;
    for (int q=start; q<end; ++q){
      const unsigned int* mp = msg + (size_t)q*320;
#pragma unroll
      for (int k=0;k<5;++k){
        const unsigned int v = mp[k*64 + lane];
        A[2*k] += h2f((unsigned short)(v & 0xffff));
        if (2*k+1 < 9) A[2*k+1] += h2f((unsigned short)(v >> 16));
      }
    }
#pragma unroll
    for (int i=0;i<9;++i) S[wid][i][lane] = A[i];
  }

  // phase 2: Amix (lane = output channel d), LDS broadcast reads of S
  float ax[9];
#pragma unroll
  for (int i=0;i<9;++i) ax[i] = 0.f;
  {
    const float* Wm0 = Wmix + (size_t)(0*10 + e)*4096;
    const float* Wm1 = Wmix + (size_t)(1*10 + e)*4096;
    const float* Wm2 = Wmix + (size_t)(2*10 + e)*4096;
    for (int c=0;c<64;++c){
      const float wv0 = Wm0[c*64+lane];
      const float wv1 = Wm1[c*64+lane];
      const float wv2 = Wm2[c*64+lane];
      ax[0] = fmaf(S[wid][0][c], wv0, ax[0]);
#pragma unroll
      for (int m=0;m<3;++m) ax[1+m] = fmaf(S[wid][1+m][c], wv1, ax[1+m]);
#pragma unroll
      for (int m=0;m<5;++m) ax[4+m] = fmaf(S[wid][4+m][c], wv2, ax[4+m]);
    }
  }
#pragma unroll
  for (int i=0;i<9;++i) ax[i] *= 0.0039528470752104741f;  // (1/AVG_NEIGH)*MIX_NORM

  // phase 3: symmetric contraction, lane-local
  const float* amix0 = ax;
  const float* amix1 = ax+1;
  const float* amix2 = ax+4;
  float w2n[5], w3n[5];
#pragma unroll
  for (int p=0;p<5;++p){
    w2n[p] = w2[(size_t)(e*5+p)*64 + lane];
    w3n[p] = w3[(size_t)(e*5+p)*64 + lane];
  }
  float t20[1] = {0.f}, t21[3] = {0.f,0.f,0.f};
  sc_accum<0,0,0>(amix0, amix0, w2n[0], t20);
  sc_accum<1,1,0>(amix1, amix1, w2n[1], t20);
  sc_accum<2,2,0>(amix2, amix2, w2n[2], t20);
  sc_accum<0,1,1>(amix0, amix1, w2n[3], t21);
  sc_accum<1,2,1>(amix1, amix2, w2n[4], t21);
  float t30[1] = {0.f}, t31[3] = {0.f,0.f,0.f};
  sc_accum<0,0,0>(t20, amix0, w3n[0], t30);
  sc_accum<1,1,0>(t21, amix1, w3n[1], t30);
  sc_accum<0,1,1>(t20, amix1, w3n[2], t31);
  sc_accum<1,0,1>(t21, amix0, w3n[3], t31);
  sc_accum<1,2,1>(t21, amix2, w3n[4], t31);

  const float w1_0 = w1[(size_t)(e*2+0)*64 + lane];
  const float w1_1 = w1[(size_t)(e*2+1)*64 + lane];
  Bb[wid][0][lane] = fmaf(w1_0, amix0[0], t20[0] + t30[0]);
#pragma unroll
  for (int m=0;m<3;++m) Bb[wid][1+m][lane] = fmaf(w1_1, amix1[m], t21[m] + t31[m]);

  // phase 4: stage h1 row into S (same wave finished reading it)
  {
    const float* hrow = h1 + (long)n*576;
#pragma unroll
    for (int r=0;r<9;++r) S[wid][r][lane] = hrow[r*64 + lane];
  }

  // phase 5: output linears (lane = d)
  float o[4];
#pragma unroll
  for (int i=0;i<4;++i) o[i] = 0.f;
  for (int c=0;c<64;++c){
    const float wh0 = Woh[c*64+lane];
    const float wh1 = Woh[4096 + c*64+lane];
    const float wm0 = Wom[c*64+lane];
    const float wm1 = Wom[4096 + c*64+lane];
    o[0] = fmaf(S[wid][0][c], wh0, o[0]);
    o[0] = fmaf(Bb[wid][0][c], wm0, o[0]);
#pragma unroll
    for (int m=0;m<3;++m){
      o[1+m] = fmaf(S[wid][1+m][c], wh1, o[1+m]);
      o[1+m] = fmaf(Bb[wid][1+m][c], wm1, o[1+m]);
    }
  }
  float* orow = out + (long)n*256;
  orow[lane] = o[0]*0.125f;
#pragma unroll
  for (int m=0;m<3;++m) orow[64+m*64+lane] = o[1+m]*0.125f;
}

// ---------------- launch ----------------
extern "C" void kernel_launch(void* const* d_in, const int* in_sizes, int n_in,
                              void* d_out, int out_size, void* d_ws, size_t ws_size,
                              hipStream_t stream){
  const int*   sender   = (const int*)  d_in[0];
  const int*   receiver = (const int*)  d_in[1];
  const int*   indices  = (const int*)  d_in[2];
  const float* node_feat= (const float*)d_in[4];
  const float* ele      = (const float*)d_in[5];
  const float* sph      = (const float*)d_in[6];
  const float* W_lin    = (const float*)d_in[7];
  const float* W0 = (const float*)d_in[8],  *b0 = (const float*)d_in[9];
  const float* W1 = (const float*)d_in[10], *b1 = (const float*)d_in[11];
  const float* W2 = (const float*)d_in[12], *b2 = (const float*)d_in[13];
  const float* W3 = (const float*)d_in[14], *b3 = (const float*)d_in[15];
  const float* Wmix = (const float*)d_in[16];
  const float* w1 = (const float*)d_in[17];
  const float* w2 = (const float*)d_in[18];
  const float* w3 = (const float*)d_in[19];
  const float* Wom = (const float*)d_in[20];
  const float* Woh = (const float*)d_in[21];
  float* out = (float*)d_out;

  char* ws = (char*)d_ws;
  const size_t OFF_H1P  = 0;                                 // 23,040,000
  const size_t OFF_HMLP = OFF_H1P  + (size_t)NNODES*576*4;   // +12,800,000
  const size_t OFF_MSG  = OFF_HMLP + (size_t)NEDGES*32*4;    // +128,000,000
  const size_t OFF_DEG  = OFF_MSG  + (size_t)NEDGES*320*4;
  const size_t OFF_ROW  = OFF_DEG  + 40960;
  const size_t OFF_CUR  = OFF_ROW  + 40964;
  const size_t OFF_EPOS = OFF_CUR  + 40960;

  float* h1p  = (float*)(ws + OFF_H1P);
  float* hmlp = (float*)(ws + OFF_HMLP);
  unsigned int* msg = (unsigned int*)(ws + OFF_MSG);
  int* deg    = (int*)(ws + OFF_DEG);
  int* rowptr = (int*)(ws + OFF_ROW);
  int* cursor = (int*)(ws + OFF_CUR);
  int* epos   = (int*)(ws + OFF_EPOS);

  k_lin_in<<<NNODES, 64, 0, stream>>>(node_feat, W_lin, h1p, deg);
  k_mlp<<<(NEDGES+255)/256, 256, 0, stream>>>(ele, W0,b0,W1,b1,W2,b2, hmlp);
  k_hist<<<(NEDGES+255)/256, 256, 0, stream>>>(receiver, deg);
  k_scan<<<1, 256, 0, stream>>>(deg, rowptr, cursor);
  k_fill_pos<<<(NEDGES+255)/256, 256, 0, stream>>>(receiver, cursor, epos);
  k_edge_pk<<<NEDGES/32, 256, 0, stream>>>(sender, epos, hmlp, sph, h1p, W3, b3, msg);
  k_node_c<<<NNODES/4, 256, 0, stream>>>(indices, node_feat, rowptr, msg,
                                         Wmix, w1, w2, w3, Wom, Woh, out);
}

// Round 17
// 246.186 us; speedup vs baseline: 1.1492x; 1.0443x over previous
//
#include <hip/hip_runtime.h>
#include <math.h>

#define NNODES 10000
#define NEDGES 100000

typedef float v2f __attribute__((ext_vector_type(2)));

// ---------------- compile-time Clebsch-Gordan (port of reference) ----------------
struct Cplx { double re, im; };

constexpr double cfact(int n){ double r=1.0; for(int i=2;i<=n;++i) r*=i; return r; }

constexpr double csqrt_(double x){
  if (x<=0.0) return 0.0;
  double g = x<1.0 ? 1.0 : x;
  for (int it=0; it<64; ++it){ double ng = 0.5*(g + x/g); if (ng==g) break; g = ng; }
  return g;
}

constexpr double cg_coeff(int j1,int m1,int j2,int m2,int j3,int m3){
  if (m1+m2!=m3) return 0.0;
  int lo = j1>j2 ? j1-j2 : j2-j1;
  if (j3<lo || j3>j1+j2) return 0.0;
  if (m1<-j1||m1>j1||m2<-j2||m2>j2||m3<-j3||m3>j3) return 0.0;
  double pre = csqrt_((2.0*j3+1.0)*cfact(j1+j2-j3)*cfact(j1-j2+j3)*cfact(-j1+j2+j3)/cfact(j1+j2+j3+1));
  pre *= csqrt_(cfact(j1+m1)*cfact(j1-m1)*cfact(j2+m2)*cfact(j2-m2)*cfact(j3+m3)*cfact(j3-m3));
  double s = 0.0;
  for (int k=0;k<=j1+j2+j3;++k){
    int d0=j1+j2-j3-k, d1=j1-m1-k, d2=j2+m2-k, d3=j3-j2+m1+k, d4=j3-j1-m2+k;
    if (d0<0||d1<0||d2<0||d3<0||d4<0) continue;
    double term = 1.0/(cfact(k)*cfact(d0)*cfact(d1)*cfact(d2)*cfact(d3)*cfact(d4));
    s += (k&1) ? -term : term;
  }
  return pre*s;
}

constexpr Cplx uent(int l,int a,int i){
  const double s = 0.70710678118654752440;
  int ma = a - l;
  if (ma==0) { if (i==l) return Cplx{1.0,0.0}; return Cplx{0.0,0.0}; }
  if (ma>0){
    int m = ma; double sg = (m&1) ? -1.0 : 1.0;
    if (i==l+m) return Cplx{sg*s, 0.0};
    if (i==l-m) return Cplx{s, 0.0};
    return Cplx{0.0,0.0};
  }
  int m = -ma; double sg = (m&1) ? -1.0 : 1.0;
  if (i==l+m) return Cplx{0.0, -sg*s};
  if (i==l-m) return Cplx{0.0, s};
  return Cplx{0.0,0.0};
}

constexpr double real_cg_entry(int l1,int l2,int l3,int a,int b,int c){
  double acc = 0.0;
  int ii0 = a, ii1 = 2*l1-a;
  int jj0 = b, jj1 = 2*l2-b;
  for (int x=0;x<2;++x){
    int i = (x==0)? ii0 : ii1;
    if (x==1 && ii1==ii0) break;
    Cplx u1 = uent(l1,a,i); if (u1.re==0.0 && u1.im==0.0) continue;
    for (int y=0;y<2;++y){
      int j = (y==0)? jj0 : jj1;
      if (y==1 && jj1==jj0) break;
      Cplx u2 = uent(l2,b,j); if (u2.re==0.0 && u2.im==0.0) continue;
      int k = (i-l1)+(j-l2)+l3;
      if (k<0 || k>2*l3) continue;
      Cplx u3 = uent(l3,c,k); if (u3.re==0.0 && u3.im==0.0) continue;
      double cg = cg_coeff(l1,i-l1,l2,j-l2,l3,k-l3);
      if (cg==0.0) continue;
      double pr = u1.re*u2.re - u1.im*u2.im;
      double pi = u1.re*u2.im + u1.im*u2.re;
      acc += (pr*u3.re + pi*u3.im) * cg;
    }
  }
  return acc;
}

struct CGT { float v[5][5][5]; };
constexpr CGT make_cg(int l1,int l2,int l3){
  CGT t{};
  for (int a=0;a<2*l1+1;++a)
    for (int b=0;b<2*l2+1;++b)
      for (int c=0;c<2*l3+1;++c)
        t.v[a][b][c] = (float)real_cg_entry(l1,l2,l3,a,b,c);
  return t;
}

// ---------------- device helpers ----------------
__device__ __forceinline__ float silu_(float x){ return x / (1.0f + __expf(-x)); }

union H16 { _Float16 h; unsigned short u; };
__device__ __forceinline__ float h2f(unsigned short u){ H16 c; c.u = u; return (float)c.h; }
__device__ __forceinline__ unsigned int pack2(float a, float b){
  H16 x, y; x.h = (_Float16)a; y.h = (_Float16)b;
  return ((unsigned int)y.u << 16) | x.u;
}
__device__ __forceinline__ v2f make2(float s){ v2f r; r.x = s; r.y = s; return r; }

// paired (2-edge) TP: msg[d] += rl * sum_{a,b} CG[a][b][d]*sp[a]*g[b]  (all v2f)
template<int L1,int L2,int L3>
__device__ __forceinline__ void tp_pk(const v2f* sp, const v2f* g, v2f rl, v2f* msg){
  constexpr CGT T = make_cg(L1,L2,L3);
  constexpr int NA = 2*L1+1, NB = 2*L2+1, ND = 2*L3+1;
  v2f t[ND];
#pragma unroll
  for (int d=0;d<ND;++d) t[d] = make2(0.f);
#pragma unroll
  for (int b=0;b<NB;++b){
#pragma unroll
    for (int d=0;d<ND;++d){
      v2f u = make2(0.f); bool any = false;
#pragma unroll
      for (int a=0;a<NA;++a){
        const float cg = T.v[a][b][d];
        if (cg != 0.f){ u = cg*sp[a] + u; any = true; }
      }
      if (any) t[d] = u*g[b] + t[d];
    }
  }
#pragma unroll
  for (int d=0;d<ND;++d) msg[d] = rl*t[d] + msg[d];
}

template<int L1,int L2,int L3>
__device__ __forceinline__ void sc_accum(const float* X, const float* Y, float w, float* out){
  constexpr CGT T = make_cg(L1,L2,L3);
  constexpr int NA = 2*L1+1, NB = 2*L2+1, ND = 2*L3+1;
#pragma unroll
  for (int d=0;d<ND;++d){
    float s = 0.f;
#pragma unroll
    for (int a=0;a<NA;++a){
#pragma unroll
      for (int b=0;b<NB;++b){
        const float cg = T.v[a][b][d];
        if (cg != 0.f) s = fmaf(cg*X[a], Y[b], s);
      }
    }
    out[d] = fmaf(w, s, out[d]);
  }
}

// ---------------- kernel 1: h1p = per-irrep h1 @ W_lin_in * 1/sqrt(K); zero deg ----------------
__global__ void __launch_bounds__(64) k_lin_in(const float* __restrict__ h1,
                                               const float* __restrict__ W,
                                               float* __restrict__ h1p,
                                               int* __restrict__ deg){
  const int n = blockIdx.x;
  const int d = threadIdx.x;
  if (d == 0) deg[n] = 0;
  const float* row = h1 + (long)n*576;
  float acc[9];
#pragma unroll
  for (int i=0;i<9;++i) acc[i] = 0.f;
  for (int c=0;c<64;++c){
    const float w0 = W[c*64 + d];
    const float w1 = W[4096 + c*64 + d];
    const float w2 = W[8192 + c*64 + d];
    acc[0] = fmaf(row[c], w0, acc[0]);
#pragma unroll
    for (int m=0;m<3;++m) acc[1+m] = fmaf(row[64+m*64+c], w1, acc[1+m]);
#pragma unroll
    for (int m=0;m<5;++m) acc[4+m] = fmaf(row[256+m*64+c], w2, acc[4+m]);
  }
  float* o = h1p + (long)n*576;
  o[d] = acc[0]*0.125f;
#pragma unroll
  for (int m=0;m<3;++m) o[64+m*64+d] = acc[1+m]*0.125f;
#pragma unroll
  for (int m=0;m<5;++m) o[256+m*64+d] = acc[4+m]*0.125f;
}

// ---------------- kernel 1b: radial MLP hidden layers + receiver histogram (fused) ----------------
// deg was zeroed by the preceding k_lin_in dispatch -> no race.
__global__ void __launch_bounds__(256) k_mlp(const float* __restrict__ ele,
                                             const float* __restrict__ W0, const float* __restrict__ b0,
                                             const float* __restrict__ W1, const float* __restrict__ b1,
                                             const float* __restrict__ W2, const float* __restrict__ b2,
                                             const int* __restrict__ receiver,
                                             int* __restrict__ deg,
                                             float* __restrict__ hmlp){
  const int e = blockIdx.x*256 + threadIdx.x;
  if (e >= NEDGES) return;
  atomicAdd(&deg[receiver[e]], 1);
  float x[8];
#pragma unroll
  for (int i=0;i<8;++i) x[i] = ele[(long)e*8 + i];
  float h[32];
#pragma unroll
  for (int d=0;d<32;++d){
    float acc = b0[d];
#pragma unroll
    for (int i=0;i<8;++i) acc = fmaf(x[i], W0[i*32+d], acc);
    h[d] = silu_(acc);
  }
#pragma unroll
  for (int L=0; L<2; ++L){
    const float* Wl = L ? W2 : W1;
    const float* bl = L ? b2 : b1;
    float acc[32];
#pragma unroll
    for (int d=0;d<32;++d) acc[d] = bl[d];
    for (int j=0;j<32;++j){
      const float hj = h[j];
#pragma unroll
      for (int d=0;d<32;++d) acc[d] = fmaf(hj, Wl[j*32+d], acc[d]);
    }
#pragma unroll
    for (int d=0;d<32;++d) h[d] += silu_(acc[d]);
  }
  float* o = hmlp + (long)e*32;
#pragma unroll
  for (int d=0;d<32;++d) o[d] = h[d];
}

// ---------------- CSR scan (rowptr + cursor) ----------------
__global__ void __launch_bounds__(256) k_scan(const int* __restrict__ deg,
                                              int* __restrict__ rowptr,
                                              int* __restrict__ cursor){
  __shared__ int sums[256];
  const int t = threadIdx.x;
  const int CH = 40;
  const int base = t*CH;
  int s = 0;
  for (int i=0;i<CH;++i){ int idx = base+i; if (idx < NNODES) s += deg[idx]; }
  sums[t] = s; __syncthreads();
  for (int off=1; off<256; off<<=1){
    int v = (t>=off) ? sums[t-off] : 0;
    __syncthreads();
    sums[t] += v;
    __syncthreads();
  }
  int run = (t==0) ? 0 : sums[t-1];
  for (int i=0;i<CH;++i){
    int idx = base+i;
    if (idx < NNODES){ rowptr[idx] = run; cursor[idx] = run; run += deg[idx]; }
  }
  if (t==255) rowptr[NNODES] = sums[255];
}

// ---------------- kernel 2: edge kernel, 8 edges/wave as 4 pairs; CSR position claimed in-kernel ----------------
// Lanes 0..7 claim positions via atomicAdd(cursor[receiver]) (cursor = rowptr copy from k_scan),
// broadcast via readlane -- removes the separate k_fill_pos dispatch. Position order within a
// receiver segment is schedule-dependent, but k_node_c sums the segment (same property as before).
__global__ void __launch_bounds__(256) k_edge_pk(const int* __restrict__ sender,
                                             const int* __restrict__ receiver,
                                             int* __restrict__ cursor,
                                             const float* __restrict__ hmlp,
                                             const float* __restrict__ sph,
                                             const float* __restrict__ h1p,
                                             const float* __restrict__ W3, const float* __restrict__ b3,
                                             unsigned int* __restrict__ msg){
  __shared__ float sps[4][72];   // [a][8] per wave
  const int wid  = threadIdx.x >> 6;
  const int lane = threadIdx.x & 63;
  const int ubase = __builtin_amdgcn_readfirstlane((blockIdx.x*4 + wid) * 8);

  {
    const int idx = lane;                       // 0..63
    const int e = idx/9, a = idx - 9*e;
    sps[wid][a*8 + e] = sph[(long)ubase*9 + idx];
  }
  if (lane < 8){
    const int idx = 64 + lane;                  // 64..71
    const int e = idx/9, a = idx - 9*e;
    sps[wid][a*8 + e] = sph[(long)ubase*9 + idx];
  }

  // claim CSR positions: lane e handles edge ubase+e
  int myp = 0;
  if (lane < 8){
    const int r = receiver[ubase + lane];
    myp = atomicAdd(&cursor[r], 1);
  }
  int pos[8];
#pragma unroll
  for (int e=0;e<8;++e) pos[e] = __builtin_amdgcn_readlane(myp, e);

  int sidx[8];
#pragma unroll
  for (int e=0;e<8;++e) sidx[e] = sender[ubase+e];

  // gather sender features as pairs (issued early; latency hidden by rl GEMM)
  v2f g2[4][9];
#pragma unroll
  for (int q=0;q<4;++q){
    const float* hp0 = h1p + (long)sidx[2*q]  *576;
    const float* hp1 = h1p + (long)sidx[2*q+1]*576;
#pragma unroll
    for (int i=0;i<9;++i){ g2[q][i].x = hp0[i*64+lane]; g2[q][i].y = hp1[i*64+lane]; }
  }
#pragma unroll
  for (int q=0;q<4;++q)
#pragma unroll
    for (int i=0;i<9;++i) asm volatile("" : "+v"(g2[q][i]));

  const float* hu = hmlp + (long)ubase*32;   // wave-uniform -> s_load

  // rl GEMM (paired): rl2[p][q] += h2{e0,e1} * w3v[p] (splat)
  v2f rl2[11][4];
#pragma unroll
  for (int p=0;p<11;++p){
    const float bb = b3[p*64+lane];
#pragma unroll
    for (int q=0;q<4;++q) rl2[p][q] = make2(bb);
  }
  for (int jb=0;jb<32;jb+=4){
    float w3v[4][11];
#pragma unroll
    for (int jj=0;jj<4;++jj)
#pragma unroll
      for (int p=0;p<11;++p)
        w3v[jj][p] = W3[(jb+jj)*704 + p*64 + lane];
#pragma unroll
    for (int q=0;q<4;++q){
#pragma unroll
      for (int jj=0;jj<4;++jj){
        v2f h2; h2.x = hu[(2*q)*32 + jb + jj]; h2.y = hu[(2*q+1)*32 + jb + jj];
#pragma unroll
        for (int p=0;p<11;++p) rl2[p][q] = h2*w3v[jj][p] + rl2[p][q];
      }
    }
  }

  // TP (paired) + packed f16 store at CSR positions
#pragma unroll
  for (int q=0;q<4;++q){
    v2f sp2[9];
#pragma unroll
    for (int a=0;a<9;++a) sp2[a] = *(const v2f*)&sps[wid][a*8 + 2*q];
    v2f m0[1]; m0[0] = make2(0.f);
    v2f m1[3]; m1[0]=m1[1]=m1[2]=make2(0.f);
    v2f m2[5]; m2[0]=m2[1]=m2[2]=m2[3]=m2[4]=make2(0.f);
    tp_pk<0,0,0>(sp2+0, &g2[q][0], rl2[0][q],  m0);
    tp_pk<0,1,1>(sp2+0, &g2[q][1], rl2[1][q],  m1);
    tp_pk<0,2,2>(sp2+0, &g2[q][4], rl2[2][q],  m2);
    tp_pk<1,0,1>(sp2+1, &g2[q][0], rl2[3][q],  m1);
    tp_pk<1,1,0>(sp2+1, &g2[q][1], rl2[4][q],  m0);
    tp_pk<1,1,2>(sp2+1, &g2[q][1], rl2[5][q],  m2);
    tp_pk<1,2,1>(sp2+1, &g2[q][4], rl2[6][q],  m1);
    tp_pk<2,0,2>(sp2+4, &g2[q][0], rl2[7][q],  m2);
    tp_pk<2,1,1>(sp2+4, &g2[q][1], rl2[8][q],  m1);
    tp_pk<2,2,0>(sp2+4, &g2[q][4], rl2[9][q],  m0);
    tp_pk<2,2,2>(sp2+4, &g2[q][4], rl2[10][q], m2);
    // edge 2q (x half)
    {
      unsigned int pk[5];
      pk[0] = pack2(m0[0].x, m1[0].x);
      pk[1] = pack2(m1[1].x, m1[2].x);
      pk[2] = pack2(m2[0].x, m2[1].x);
      pk[3] = pack2(m2[2].x, m2[3].x);
      pk[4] = pack2(m2[4].x, 0.f);
      unsigned int* mp = msg + (size_t)pos[2*q]*320;
#pragma unroll
      for (int k=0;k<5;++k) mp[k*64 + lane] = pk[k];
    }
    // edge 2q+1 (y half)
    {
      unsigned int pk[5];
      pk[0] = pack2(m0[0].y, m1[0].y);
      pk[1] = pack2(m1[1].y, m1[2].y);
      pk[2] = pack2(m2[0].y, m2[1].y);
      pk[3] = pack2(m2[2].y, m2[3].y);
      pk[4] = pack2(m2[4].y, 0.f);
      unsigned int* mp = msg + (size_t)pos[2*q+1]*320;
#pragma unroll
      for (int k=0;k<5;++k) mp[k*64 + lane] = pk[k];
    }
  }
}

// ---------------- kernel 3: node kernel, 1 wave/node, contiguous CSR message read ----------------
__global__ void __launch_bounds__(256) k_node_c(const int* __restrict__ indices,
                                             const float* __restrict__ h1,
                                             const int* __restrict__ rowptr,
                                             const unsigned int* __restrict__ msg,
                                             const float* __restrict__ Wmix,
                                             const float* __restrict__ w1,
                                             const float* __restrict__ w2,
                                             const float* __restrict__ w3,
                                             const float* __restrict__ Wom,
                                             const float* __restrict__ Woh,
                                             float* __restrict__ out){
  __shared__ float S[4][9][64];
  __shared__ float Bb[4][4][64];
  const int wid  = threadIdx.x >> 6;
  const int lane = threadIdx.x & 63;
  const int n = blockIdx.x*4 + wid;
  const int e = __builtin_amdgcn_readfirstlane(indices[n]);

  // phase 1: contiguous gather-sum of incoming messages (lane = channel c) -> LDS
  {
    const int start = rowptr[n], end = rowptr[n+1];
    float A[9];
#pragma unroll
    for (int i=0;i<9;++i) A[i] = 0.f;
    for (int q=start; q<end; ++q){
      const unsigned int* mp = msg + (size_t)q*320;
#pragma unroll
      for (int k=0;k<5;++k){
        const unsigned int v = mp[k*64 + lane];
        A[2*k] += h2f((unsigned short)(v & 0xffff));
        if (2*k+1 < 9) A[2*k+1] += h2f((unsigned short)(v >> 16));
      }
    }
#pragma unroll
    for (int i=0;i<9;++i) S[wid][i][lane] = A[i];
  }

  // phase 2: Amix (lane = output channel d), LDS broadcast reads of S
  float ax[9];
#pragma unroll
  for (int i=0;i<9;++i) ax[i] = 0.f;
  {
    const float* Wm0 = Wmix + (size_t)(0*10 + e)*4096;
    const float* Wm1 = Wmix + (size_t)(1*10 + e)*4096;
    const float* Wm2 = Wmix + (size_t)(2*10 + e)*4096;
    for (int c=0;c<64;++c){
      const float wv0 = Wm0[c*64+lane];
      const float wv1 = Wm1[c*64+lane];
      const float wv2 = Wm2[c*64+lane];
      ax[0] = fmaf(S[wid][0][c], wv0, ax[0]);
#pragma unroll
      for (int m=0;m<3;++m) ax[1+m] = fmaf(S[wid][1+m][c], wv1, ax[1+m]);
#pragma unroll
      for (int m=0;m<5;++m) ax[4+m] = fmaf(S[wid][4+m][c], wv2, ax[4+m]);
    }
  }
#pragma unroll
  for (int i=0;i<9;++i) ax[i] *= 0.0039528470752104741f;  // (1/AVG_NEIGH)*MIX_NORM

  // phase 3: symmetric contraction, lane-local
  const float* amix0 = ax;
  const float* amix1 = ax+1;
  const float* amix2 = ax+4;
  float w2n[5], w3n[5];
#pragma unroll
  for (int p=0;p<5;++p){
    w2n[p] = w2[(size_t)(e*5+p)*64 + lane];
    w3n[p] = w3[(size_t)(e*5+p)*64 + lane];
  }
  float t20[1] = {0.f}, t21[3] = {0.f,0.f,0.f};
  sc_accum<0,0,0>(amix0, amix0, w2n[0], t20);
  sc_accum<1,1,0>(amix1, amix1, w2n[1], t20);
  sc_accum<2,2,0>(amix2, amix2, w2n[2], t20);
  sc_accum<0,1,1>(amix0, amix1, w2n[3], t21);
  sc_accum<1,2,1>(amix1, amix2, w2n[4], t21);
  float t30[1] = {0.f}, t31[3] = {0.f,0.f,0.f};
  sc_accum<0,0,0>(t20, amix0, w3n[0], t30);
  sc_accum<1,1,0>(t21, amix1, w3n[1], t30);
  sc_accum<0,1,1>(t20, amix1, w3n[2], t31);
  sc_accum<1,0,1>(t21, amix0, w3n[3], t31);
  sc_accum<1,2,1>(t21, amix2, w3n[4], t31);

  const float w1_0 = w1[(size_t)(e*2+0)*64 + lane];
  const float w1_1 = w1[(size_t)(e*2+1)*64 + lane];
  Bb[wid][0][lane] = fmaf(w1_0, amix0[0], t20[0] + t30[0]);
#pragma unroll
  for (int m=0;m<3;++m) Bb[wid][1+m][lane] = fmaf(w1_1, amix1[m], t21[m] + t31[m]);

  // phase 4: stage h1 row into S (same wave finished reading it)
  {
    const float* hrow = h1 + (long)n*576;
#pragma unroll
    for (int r=0;r<9;++r) S[wid][r][lane] = hrow[r*64 + lane];
  }

  // phase 5: output linears (lane = d)
  float o[4];
#pragma unroll
  for (int i=0;i<4;++i) o[i] = 0.f;
  for (int c=0;c<64;++c){
    const float wh0 = Woh[c*64+lane];
    const float wh1 = Woh[4096 + c*64+lane];
    const float wm0 = Wom[c*64+lane];
    const float wm1 = Wom[4096 + c*64+lane];
    o[0] = fmaf(S[wid][0][c], wh0, o[0]);
    o[0] = fmaf(Bb[wid][0][c], wm0, o[0]);
#pragma unroll
    for (int m=0;m<3;++m){
      o[1+m] = fmaf(S[wid][1+m][c], wh1, o[1+m]);
      o[1+m] = fmaf(Bb[wid][1+m][c], wm1, o[1+m]);
    }
  }
  float* orow = out + (long)n*256;
  orow[lane] = o[0]*0.125f;
#pragma unroll
  for (int m=0;m<3;++m) orow[64+m*64+lane] = o[1+m]*0.125f;
}

// ---------------- launch ----------------
extern "C" void kernel_launch(void* const* d_in, const int* in_sizes, int n_in,
                              void* d_out, int out_size, void* d_ws, size_t ws_size,
                              hipStream_t stream){
  const int*   sender   = (const int*)  d_in[0];
  const int*   receiver = (const int*)  d_in[1];
  const int*   indices  = (const int*)  d_in[2];
  const float* node_feat= (const float*)d_in[4];
  const float* ele      = (const float*)d_in[5];
  const float* sph      = (const float*)d_in[6];
  const float* W_lin    = (const float*)d_in[7];
  const float* W0 = (const float*)d_in[8],  *b0 = (const float*)d_in[9];
  const float* W1 = (const float*)d_in[10], *b1 = (const float*)d_in[11];
  const float* W2 = (const float*)d_in[12], *b2 = (const float*)d_in[13];
  const float* W3 = (const float*)d_in[14], *b3 = (const float*)d_in[15];
  const float* Wmix = (const float*)d_in[16];
  const float* w1 = (const float*)d_in[17];
  const float* w2 = (const float*)d_in[18];
  const float* w3 = (const float*)d_in[19];
  const float* Wom = (const float*)d_in[20];
  const float* Woh = (const float*)d_in[21];
  float* out = (float*)d_out;

  char* ws = (char*)d_ws;
  const size_t OFF_H1P  = 0;                                 // 23,040,000
  const size_t OFF_HMLP = OFF_H1P  + (size_t)NNODES*576*4;   // +12,800,000
  const size_t OFF_MSG  = OFF_HMLP + (size_t)NEDGES*32*4;    // +128,000,000
  const size_t OFF_DEG  = OFF_MSG  + (size_t)NEDGES*320*4;
  const size_t OFF_ROW  = OFF_DEG  + 40960;
  const size_t OFF_CUR  = OFF_ROW  + 40964;

  float* h1p  = (float*)(ws + OFF_H1P);
  float* hmlp = (float*)(ws + OFF_HMLP);
  unsigned int* msg = (unsigned int*)(ws + OFF_MSG);
  int* deg    = (int*)(ws + OFF_DEG);
  int* rowptr = (int*)(ws + OFF_ROW);
  int* cursor = (int*)(ws + OFF_CUR);

  k_lin_in<<<NNODES, 64, 0, stream>>>(node_feat, W_lin, h1p, deg);
  k_mlp<<<(NEDGES+255)/256, 256, 0, stream>>>(ele, W0,b0,W1,b1,W2,b2,
                                              receiver, deg, hmlp);
  k_scan<<<1, 256, 0, stream>>>(deg, rowptr, cursor);
  k_edge_pk<<<NEDGES/32, 256, 0, stream>>>(sender, receiver, cursor, hmlp, sph, h1p,
                                           W3, b3, msg);
  k_node_c<<<NNODES/4, 256, 0, stream>>>(indices, node_feat, rowptr, msg,
                                         Wmix, w1, w2, w3, Wom, Woh, out);
}